// Round 1
// baseline (380.610 us; speedup 1.0000x reference)
//
#include <hip/hip_runtime.h>

#define NB 4
#define CI 64
#define CO 128
#define HH 128
#define WW 128
#define HWSZ (HH*WW)
#define NN 9
#define KTOT 576          // CI * NN
#define ASTR 577          // LDS stride for A tile (conflict-free: 577 % 32 == 1)
#define TPX 16            // pixels per block in k_main

// ---------------- K0: transpose w_conv [oc][k] -> wT [k][oc] ----------------
__global__ __launch_bounds__(256) void k_transpose_w(const float* __restrict__ w,
                                                     float* __restrict__ wT) {
    int t = blockIdx.x * 256 + threadIdx.x;
    if (t >= CO * KTOT) return;
    int oc = t / KTOT, k = t % KTOT;
    wT[k * CO + oc] = w[t];
}

// ---------------- K1: offset conv + bilinear indices/weights ----------------
// One thread per output pixel (b,y,x). Computes all 18 offset channels, then
// for each of the 9 samples the 4 corner flat-indices (into unpadded x, per
// image) and 4 bilinear weights (0 where corner lies in the zero-pad ring).
__global__ __launch_bounds__(256) void k_offsets(
    const float* __restrict__ x, const float* __restrict__ w_off,
    const float* __restrict__ b_off, int4* __restrict__ oIdx,
    float4* __restrict__ oG)
{
    __shared__ float wl[KTOT * 20];   // [k = c*9+ky*3+kx][oc(18), padded to 20]
    for (int i = threadIdx.x; i < 18 * KTOT; i += 256) {
        int oc = i / KTOT, k = i % KTOT;
        wl[k * 20 + oc] = w_off[i];
    }
    __syncthreads();

    int tid = blockIdx.x * 256 + threadIdx.x;
    int b   = tid >> 14;
    int rem = tid & 16383;
    int y   = rem >> 7;
    int xi  = rem & 127;

    const float* xb = x + b * CI * HWSZ;
    float acc[18];
    #pragma unroll
    for (int i = 0; i < 18; i++) acc[i] = b_off[i];

    for (int c = 0; c < CI; c++) {
        const float* xc = xb + c * HWSZ;
        #pragma unroll
        for (int ky = 0; ky < 3; ky++) {
            int yy = y + ky - 1;
            bool yok = ((unsigned)yy) < 128u;
            #pragma unroll
            for (int kx = 0; kx < 3; kx++) {
                int xx = xi + kx - 1;
                float xv = (yok && ((unsigned)xx) < 128u) ? xc[yy * WW + xx] : 0.f;
                const float* wr = &wl[(c * 9 + ky * 3 + kx) * 20];
                #pragma unroll
                for (int oc = 0; oc < 18; oc++)
                    acc[oc] = fmaf(xv, wr[oc], acc[oc]);
            }
        }
    }

    #pragma unroll
    for (int n = 0; n < NN; n++) {
        float py = (float)(y + 1) + (float)(n / 3 - 1) + acc[n];
        float px = (float)(xi + 1) + (float)(n % 3 - 1) + acc[9 + n];
        float fy = floorf(py), fx = floorf(px);
        int qlt_y = min(max((int)fy, 0), HH + 1);       // clamp to [0, Hp-1=129]
        int qlt_x = min(max((int)fx, 0), WW + 1);
        int qrb_y = min(max((int)fy + 1, 0), HH + 1);
        int qrb_x = min(max((int)fx + 1, 0), WW + 1);
        // padding-region snap (mask uses ORIGINAL p; snap to floor of original p)
        if (py < 1.f || py > 128.f) py = fy;
        if (px < 1.f || px > 128.f) px = fx;
        py = fminf(fmaxf(py, 0.f), 129.f);
        px = fminf(fmaxf(px, 0.f), 129.f);

        float wyl = 1.f + ((float)qlt_y - py);
        float wyr = 1.f - ((float)qrb_y - py);
        float wxl = 1.f + ((float)qlt_x - px);
        float wxr = 1.f - ((float)qrb_x - px);

        float glt = wyl * wxl;
        float grb = wyr * wxr;
        float glb = wyl * wxr;   // (qlt_y, qrb_x)
        float grt = wyr * wxl;   // (qrb_y, qlt_x)

        // padded coords -> unpadded flat index; pad corners contribute 0
        bool vy_l = (qlt_y >= 1) && (qlt_y <= HH);
        bool vy_r = (qrb_y >= 1) && (qrb_y <= HH);
        bool vx_l = (qlt_x >= 1) && (qlt_x <= WW);
        bool vx_r = (qrb_x >= 1) && (qrb_x <= WW);

        int ilt = 0, irb = 0, ilb = 0, irt = 0;
        if (vy_l && vx_l) ilt = (qlt_y - 1) * WW + (qlt_x - 1); else glt = 0.f;
        if (vy_r && vx_r) irb = (qrb_y - 1) * WW + (qrb_x - 1); else grb = 0.f;
        if (vy_l && vx_r) ilb = (qlt_y - 1) * WW + (qrb_x - 1); else glb = 0.f;
        if (vy_r && vx_l) irt = (qrb_y - 1) * WW + (qlt_x - 1); else grt = 0.f;

        oIdx[tid * NN + n] = make_int4(ilt, irb, ilb, irt);
        oG[tid * NN + n]   = make_float4(glt, grb, glb, grt);
    }
}

// ---------------- K2: bilinear gather -> LDS, then tiled GEMM ----------------
// Block: 256 threads, 16 consecutive pixels (one row segment) x all 128 oc.
// A tile: x_off[16 px][576], B chunks: wT[64 k][128 oc] staged per K-step.
__global__ __launch_bounds__(256, 2) void k_main(
    const float* __restrict__ x, const float* __restrict__ wT,
    const int4* __restrict__ gIdx, const float4* __restrict__ gG,
    float* __restrict__ out)
{
    __shared__ float A[TPX * ASTR];      // 36.9 KB
    __shared__ float Bs[64 * CO];        // 32   KB
    __shared__ int4  sIdx[TPX * NN];     // 2.3  KB
    __shared__ float4 sG[TPX * NN];      // 2.3  KB

    int bid = blockIdx.x;
    int b   = bid >> 10;                 // 1024 tiles per image (128 rows * 8)
    int rem = bid & 1023;
    int y   = rem >> 3;
    int x0  = (rem & 7) * TPX;
    int t   = threadIdx.x;
    int pixbase = (b * HH + y) * WW + x0;

    if (t < TPX * NN) {
        sIdx[t] = gIdx[pixbase * NN + t];
        sG[t]   = gG[pixbase * NN + t];
    }
    __syncthreads();

    // ---- gather phase: build A[p][k], k = c*9 + n ----
    {
        int p = t >> 4, l = t & 15;
        const float* xb = x + b * CI * HWSZ;
        #pragma unroll 4
        for (int i = 0; i < 36; i++) {
            int k = l + (i << 4);
            int c = k / 9, n = k - c * 9;
            int4  q = sIdx[p * NN + n];
            float4 g = sG[p * NN + n];
            const float* xc = xb + c * HWSZ;
            float v = g.x * xc[q.x] + g.y * xc[q.y] + g.z * xc[q.z] + g.w * xc[q.w];
            A[p * ASTR + k] = v;
        }
    }
    __syncthreads();

    // ---- GEMM phase: each thread: 2 pixels x 4 ocs ----
    float acc[2][4];
    #pragma unroll
    for (int i = 0; i < 2; i++)
        #pragma unroll
        for (int j = 0; j < 4; j++) acc[i][j] = 0.f;

    int pp  = (t & 7) * 2;       // pixel pair base
    int oc4 = (t >> 3) * 4;      // 4 consecutive ocs

    for (int kc = 0; kc < KTOT; kc += 64) {
        // stage Bs[kk][oc]
        {
            int row = t >> 5;            // 0..7
            int col = (t & 31) * 4;      // 0..124
            #pragma unroll
            for (int r = 0; r < 8; r++) {
                int kk = row + r * 8;
                float4 v = *reinterpret_cast<const float4*>(&wT[(kc + kk) * CO + col]);
                *reinterpret_cast<float4*>(&Bs[kk * CO + col]) = v;
            }
        }
        __syncthreads();
        #pragma unroll 8
        for (int kk = 0; kk < 64; kk++) {
            float a0 = A[pp * ASTR + kc + kk];
            float a1 = A[(pp + 1) * ASTR + kc + kk];
            float4 bv = *reinterpret_cast<const float4*>(&Bs[kk * CO + oc4]);
            acc[0][0] = fmaf(a0, bv.x, acc[0][0]);
            acc[0][1] = fmaf(a0, bv.y, acc[0][1]);
            acc[0][2] = fmaf(a0, bv.z, acc[0][2]);
            acc[0][3] = fmaf(a0, bv.w, acc[0][3]);
            acc[1][0] = fmaf(a1, bv.x, acc[1][0]);
            acc[1][1] = fmaf(a1, bv.y, acc[1][1]);
            acc[1][2] = fmaf(a1, bv.z, acc[1][2]);
            acc[1][3] = fmaf(a1, bv.w, acc[1][3]);
        }
        __syncthreads();
    }

    // ---- write out: float2 (2 consecutive pixels) per oc ----
    int obase = (b * CO + oc4) * HWSZ + y * WW + x0 + pp;
    #pragma unroll
    for (int j = 0; j < 4; j++) {
        float2 v = make_float2(acc[0][j], acc[1][j]);
        *reinterpret_cast<float2*>(&out[obase + j * HWSZ]) = v;
    }
}

extern "C" void kernel_launch(void* const* d_in, const int* in_sizes, int n_in,
                              void* d_out, int out_size, void* d_ws, size_t ws_size,
                              hipStream_t stream) {
    const float* x      = (const float*)d_in[0];
    const float* w_off  = (const float*)d_in[1];
    const float* b_off  = (const float*)d_in[2];
    const float* w_conv = (const float*)d_in[3];
    float* out = (float*)d_out;

    const size_t n_entries = (size_t)NB * HWSZ * NN;           // 589824
    int4*   oIdx = (int4*)d_ws;
    float4* oG   = (float4*)((char*)d_ws + n_entries * sizeof(int4));
    float*  wT   = (float*)((char*)d_ws + 2 * n_entries * sizeof(int4));

    k_transpose_w<<<(CO * KTOT + 255) / 256, 256, 0, stream>>>(w_conv, wT);
    k_offsets<<<(NB * HWSZ) / 256, 256, 0, stream>>>(x, w_off, b_off, oIdx, oG);
    k_main<<<NB * HWSZ / TPX, 256, 0, stream>>>(x, wT, oIdx, oG, out);
}

// Round 2
// 188.789 us; speedup vs baseline: 2.0161x; 2.0161x over previous
//
#include <hip/hip_runtime.h>

#define NB 4
#define CI 64
#define CO 128
#define HH 128
#define WW 128
#define HWSZ (HH*WW)
#define NN 9
#define KTOT 576            // = NN * CI, k = n*64 + c ordering

using short8 = __attribute__((ext_vector_type(8))) short;
using f32x4  = __attribute__((ext_vector_type(4))) float;

__device__ __forceinline__ unsigned f2bf(float f) {      // fp32 -> bf16 bits, RNE
    unsigned u = __float_as_uint(f);
    return (u + 0x7FFFu + ((u >> 16) & 1u)) >> 16;
}

// -------- K0: w_conv [oc][c][3][3] -> ws, bf16, chunked+XOR-swizzled ---------
// ws layout: [kc=n 0..8][16KB chunk]: byte = oc*128 + ((g ^ (oc&7))<<4) + (k&7)*2
__global__ __launch_bounds__(256) void k_prep_w(const float* __restrict__ w,
                                                unsigned char* __restrict__ wsW) {
    int t = blockIdx.x * 256 + threadIdx.x;   // t = oc*576 + c*9 + n (coalesced read)
    if (t >= CO * KTOT) return;
    int oc = t / KTOT, r = t - oc * KTOT;
    int c = r / 9, n = r - c * 9;
    int k = n * 64 + c;
    int kc = k >> 6, g = (k >> 3) & 7;
    int addr = kc * 16384 + oc * 128 + ((g ^ (oc & 7)) << 4) + (k & 7) * 2;
    *(unsigned short*)(wsW + addr) = (unsigned short)f2bf(w[t]);
}

// ---------------- K1: offset conv + bilinear corner tables ----------------
// Per output pixel: 18 offset channels, then per sample n: corner coords
// (y0,y1,x0,x1 unpadded, clamped; invalid corners get weight 0) + 4 weights.
__global__ __launch_bounds__(256) void k_offsets(
    const float* __restrict__ x, const float* __restrict__ w_off,
    const float* __restrict__ b_off, uchar4* __restrict__ corU,
    float4* __restrict__ gW)
{
    __shared__ float wl[KTOT * 20];   // [k = c*9+ky*3+kx][oc(18), padded to 20]
    for (int i = threadIdx.x; i < 18 * KTOT; i += 256) {
        int oc = i / KTOT, k = i % KTOT;
        wl[k * 20 + oc] = w_off[i];
    }
    __syncthreads();

    int tid = blockIdx.x * 256 + threadIdx.x;
    int b   = tid >> 14;
    int rem = tid & 16383;
    int y   = rem >> 7;
    int xi  = rem & 127;

    const float* xb = x + b * CI * HWSZ;
    float acc[18];
    #pragma unroll
    for (int i = 0; i < 18; i++) acc[i] = b_off[i];

    for (int c = 0; c < CI; c++) {
        const float* xc = xb + c * HWSZ;
        #pragma unroll
        for (int ky = 0; ky < 3; ky++) {
            int yy = y + ky - 1;
            bool yok = ((unsigned)yy) < 128u;
            #pragma unroll
            for (int kx = 0; kx < 3; kx++) {
                int xx = xi + kx - 1;
                float xv = (yok && ((unsigned)xx) < 128u) ? xc[yy * WW + xx] : 0.f;
                const float* wr = &wl[(c * 9 + ky * 3 + kx) * 20];
                #pragma unroll
                for (int oc = 0; oc < 18; oc++)
                    acc[oc] = fmaf(xv, wr[oc], acc[oc]);
            }
        }
    }

    #pragma unroll
    for (int n = 0; n < NN; n++) {
        float py = (float)(y + 1) + (float)(n / 3 - 1) + acc[n];
        float px = (float)(xi + 1) + (float)(n % 3 - 1) + acc[9 + n];
        float fy = floorf(py), fx = floorf(px);
        int y0 = min(max((int)fy, 0), HH + 1);          // padded coords [0,129]
        int x0 = min(max((int)fx, 0), WW + 1);
        int y1 = min(max((int)fy + 1, 0), HH + 1);
        int x1 = min(max((int)fx + 1, 0), WW + 1);
        // padding-region snap (mask uses ORIGINAL p; snap to floor of original p)
        if (py < 1.f || py > 128.f) py = fy;
        if (px < 1.f || px > 128.f) px = fx;
        py = fminf(fmaxf(py, 0.f), 129.f);
        px = fminf(fmaxf(px, 0.f), 129.f);

        float wyl = 1.f + ((float)y0 - py);
        float wyr = 1.f - ((float)y1 - py);
        float wxl = 1.f + ((float)x0 - px);
        float wxr = 1.f - ((float)x1 - px);

        float glt = wyl * wxl;   // (y0,x0)
        float grb = wyr * wxr;   // (y1,x1)
        float glb = wyl * wxr;   // (y0,x1)
        float grt = wyr * wxl;   // (y1,x0)

        bool vyl = (y0 >= 1) && (y0 <= HH);
        bool vyr = (y1 >= 1) && (y1 <= HH);
        bool vxl = (x0 >= 1) && (x0 <= WW);
        bool vxr = (x1 >= 1) && (x1 <= WW);
        if (!(vyl && vxl)) glt = 0.f;
        if (!(vyr && vxr)) grb = 0.f;
        if (!(vyl && vxr)) glb = 0.f;
        if (!(vyr && vxl)) grt = 0.f;

        uchar4 cu;
        cu.x = (unsigned char)min(max(y0 - 1, 0), HH - 1);   // y0 unpadded
        cu.y = (unsigned char)min(max(y1 - 1, 0), HH - 1);   // y1
        cu.z = (unsigned char)min(max(x0 - 1, 0), WW - 1);   // x0
        cu.w = (unsigned char)min(max(x1 - 1, 0), WW - 1);   // x1
        corU[tid * NN + n] = cu;
        gW[tid * NN + n]   = make_float4(glt, grb, glb, grt);
    }
}

// ------- K2 (fused): bilinear gather -> swizzled bf16 LDS -> MFMA GEMM -------
// Block = one image row (128 px) x all 128 oc. 9 K-chunks (one sample n each).
__global__ __launch_bounds__(256) void k_main(
    const float* __restrict__ x, const unsigned char* __restrict__ wsW,
    const uchar4* __restrict__ corU, const float4* __restrict__ gW,
    float* __restrict__ out)
{
    __shared__ short Wl[8192];   // 16KB: [oc 128][k 64] bf16, XOR-swizzled
    __shared__ short Al[8192];   // 16KB: [px 128][k 64] bf16, XOR-swizzled

    // XCD-bijective swizzle: nwg=512 = 8 XCDs x 64 contiguous rows
    int bid0 = blockIdx.x;
    int bid  = ((bid0 & 7) << 6) | (bid0 >> 3);
    int b = bid >> 7, y = bid & 127;

    int t = threadIdx.x;
    int lane = t & 63, wv = t >> 6;
    int px = t & 127, chalf = t >> 7;         // gather role: pixel + channel-half
    int row = lane & 15, koct = lane >> 4;    // MFMA fragment role
    int ocw = (wv >> 1) << 6, pxw = (wv & 1) << 6;   // wave tile: 64oc x 64px

    int baseW[4], baseX[4];
    #pragma unroll
    for (int i = 0; i < 4; i++) {
        int oc_l = ocw + i * 16 + row;
        baseW[i] = oc_l * 128 + (((oc_l & 7) ^ koct) << 4);
        int px_l = pxw + i * 16 + row;
        baseX[i] = px_l * 128 + (((px_l & 7) ^ koct) << 4);
    }

    f32x4 acc[4][4];
    #pragma unroll
    for (int i = 0; i < 4; i++)
        #pragma unroll
        for (int j = 0; j < 4; j++) acc[i][j] = {0.f, 0.f, 0.f, 0.f};

    const float* xb = x + (size_t)(b * CI + chalf * 32) * HWSZ;
    int pxg9 = ((b * HH + y) * WW + px) * NN;
    int wrbase = px * 128;
    int swz = px & 7;

    for (int kc = 0; kc < 9; kc++) {
        // ---- stage W chunk (16KB, reg->LDS, conflict-free b128) ----
        {
            const uint4* src = (const uint4*)(wsW + kc * 16384) + t;
            #pragma unroll
            for (int p = 0; p < 4; p++) {
                uint4 v = src[p * 256];
                *(uint4*)((char*)Wl + t * 16 + p * 4096) = v;
            }
        }
        // ---- gather A chunk: sample n=kc, 32 channels per thread ----
        {
            uchar4 cu = corU[pxg9 + kc];
            float4 g  = gW[pxg9 + kc];
            int o00 = cu.x * WW + cu.z, o11 = cu.y * WW + cu.w;
            int o01 = cu.x * WW + cu.w, o10 = cu.y * WW + cu.z;
            #pragma unroll
            for (int cc = 0; cc < 32; cc += 4) {
                float v[4];
                #pragma unroll
                for (int q = 0; q < 4; q++) {
                    const float* xc = xb + (cc + q) * HWSZ;
                    v[q] = g.x * xc[o00] + g.y * xc[o11] + g.z * xc[o01] + g.w * xc[o10];
                }
                unsigned lo = f2bf(v[0]) | (f2bf(v[1]) << 16);
                unsigned hi = f2bf(v[2]) | (f2bf(v[3]) << 16);
                int k = chalf * 32 + cc;
                int addr = wrbase + ((((k >> 3) & 7) ^ swz) << 4) + (k & 7) * 2;
                uint2 u; u.x = lo; u.y = hi;
                *(uint2*)((char*)Al + addr) = u;
            }
        }
        __syncthreads();

        // ---- MFMA: 2 k-steps x 16 mfma (wave tile 64oc x 64px) ----
        #pragma unroll
        for (int ks = 0; ks < 2; ks++) {
            short8 af[4], bf[4];
            #pragma unroll
            for (int i = 0; i < 4; i++)
                af[i] = *(const short8*)((const char*)Wl + (baseW[i] ^ (ks << 6)));
            #pragma unroll
            for (int j = 0; j < 4; j++)
                bf[j] = *(const short8*)((const char*)Al + (baseX[j] ^ (ks << 6)));
            #pragma unroll
            for (int i = 0; i < 4; i++)
                #pragma unroll
                for (int j = 0; j < 4; j++)
                    acc[i][j] = __builtin_amdgcn_mfma_f32_16x16x32_bf16(
                        af[i], bf[j], acc[i][j], 0, 0, 0);
        }
        __syncthreads();
    }

    // ---- epilogue: D[oc][px], col=lane&15 -> px (64B coalesced), row -> oc ----
    int obase = (b * CO) * HWSZ + y * WW;
    #pragma unroll
    for (int i = 0; i < 4; i++) {
        #pragma unroll
        for (int j = 0; j < 4; j++) {
            #pragma unroll
            for (int r = 0; r < 4; r++) {
                int oc = ocw + i * 16 + koct * 4 + r;
                out[obase + oc * HWSZ + pxw + j * 16 + row] = acc[i][j][r];
            }
        }
    }
}

extern "C" void kernel_launch(void* const* d_in, const int* in_sizes, int n_in,
                              void* d_out, int out_size, void* d_ws, size_t ws_size,
                              hipStream_t stream) {
    const float* x      = (const float*)d_in[0];
    const float* w_off  = (const float*)d_in[1];
    const float* b_off  = (const float*)d_in[2];
    const float* w_conv = (const float*)d_in[3];
    float* out = (float*)d_out;

    const size_t n_samp = (size_t)NB * HWSZ * NN;            // 589824
    uchar4*        corU = (uchar4*)d_ws;                     // 2.36 MB
    float4*        gWt  = (float4*)((char*)d_ws + n_samp * 4);        // 9.44 MB
    unsigned char* wsW  = (unsigned char*)d_ws + n_samp * 4 + n_samp * 16;  // 147 KB

    k_prep_w<<<(CO * KTOT + 255) / 256, 256, 0, stream>>>(w_conv, wsW);
    k_offsets<<<(NB * HWSZ) / 256, 256, 0, stream>>>(x, w_off, b_off, corU, gWt);
    k_main<<<NB * HH, 256, 0, stream>>>(x, wsW, corU, gWt, out);
}

// Round 3
// 103.496 us; speedup vs baseline: 3.6775x; 1.8241x over previous
//
#include <hip/hip_runtime.h>

#define NB 4
#define CI 64
#define CO 128
#define HH 128
#define WW 128
#define HWSZ (HH*WW)
#define TOTPX (NB*HWSZ)     // 65536
#define NN 9

using short8 = __attribute__((ext_vector_type(8))) short;
using f32x4  = __attribute__((ext_vector_type(4))) float;

__device__ __forceinline__ unsigned f2bf(float f) {      // fp32 -> bf16 bits, RNE
    unsigned u = __float_as_uint(f);
    return (u + 0x7FFFu + ((u >> 16) & 1u)) >> 16;
}

// -------- K0: w_conv[oc][c][3][3] -> wsW bf16 [n][oc][c] (plain rows) --------
__global__ __launch_bounds__(256) void k_prep_w(const float* __restrict__ w,
                                                unsigned short* __restrict__ wsW) {
    int t = blockIdx.x * 256 + threadIdx.x;
    if (t >= CO * 576) return;
    int oc = t / 576, r = t - oc * 576;
    int c = r / 9, n = r - c * 9;
    wsW[(n * CO + oc) * 64 + c] = (unsigned short)f2bf(w[t]);
}

// ---------------- K0b: x NCHW -> xT NHWC (LDS transpose) ----------------
__global__ __launch_bounds__(256) void k_nhwc(const float* __restrict__ x,
                                              float* __restrict__ xT) {
    __shared__ float tl[64 * 65];
    int bid = blockIdx.x;
    int b = bid >> 8, rem = bid & 255, y = rem >> 1, x0 = (rem & 1) << 6;
    int t = threadIdx.x;
    #pragma unroll
    for (int i = 0; i < 16; i++) {
        int idx = t + i * 256;
        int c = idx >> 6, xl = idx & 63;
        tl[c * 65 + xl] = x[((size_t)(b * CI + c) * HH + y) * WW + x0 + xl];
    }
    __syncthreads();
    #pragma unroll
    for (int i = 0; i < 16; i++) {
        int idx = t + i * 256;
        int xl = idx >> 6, c = idx & 63;
        xT[(size_t)((b * HH + y) * WW + x0 + xl) * 64 + c] = tl[c * 65 + xl];
    }
}

// ------- K1: offset conv (4-way channel split) -> final sample coords -------
__global__ __launch_bounds__(256) void k_offsets(
    const float* __restrict__ x, const float* __restrict__ w_off,
    const float* __restrict__ b_off, float2* __restrict__ pT)
{
    __shared__ float smem[576 * 20];   // phase1: weights [k][oc pad20]; phase2: partials
    int bid = blockIdx.x;
    int b = bid >> 8, rem = bid & 255, y = rem >> 1, x0 = (rem & 1) << 6;
    int t = threadIdx.x;
    for (int i = t; i < 18 * 576; i += 256) {
        int oc = i / 576, k = i - oc * 576;
        smem[k * 20 + oc] = w_off[i];
    }
    __syncthreads();

    int pxl = t & 63, cq = t >> 6;
    int xg = x0 + pxl;
    float a[18];
    #pragma unroll
    for (int i = 0; i < 18; i++) a[i] = 0.f;

    const float* xb = x + (size_t)(b * CI + cq * 16) * HWSZ;
    for (int ci = 0; ci < 16; ci++) {
        const float* xc = xb + ci * HWSZ;
        int cg = cq * 16 + ci;
        #pragma unroll
        for (int ky = 0; ky < 3; ky++) {
            int yy = y + ky - 1;
            bool yok = (unsigned)yy < 128u;
            #pragma unroll
            for (int kx = 0; kx < 3; kx++) {
                int xx = xg + kx - 1;
                float xv = (yok && (unsigned)xx < 128u) ? xc[yy * WW + xx] : 0.f;
                const f32x4* wr = (const f32x4*)&smem[(cg * 9 + ky * 3 + kx) * 20];
                f32x4 w0 = wr[0], w1 = wr[1], w2 = wr[2], w3 = wr[3], w4 = wr[4];
                a[0]  = fmaf(xv, w0[0], a[0]);   a[1]  = fmaf(xv, w0[1], a[1]);
                a[2]  = fmaf(xv, w0[2], a[2]);   a[3]  = fmaf(xv, w0[3], a[3]);
                a[4]  = fmaf(xv, w1[0], a[4]);   a[5]  = fmaf(xv, w1[1], a[5]);
                a[6]  = fmaf(xv, w1[2], a[6]);   a[7]  = fmaf(xv, w1[3], a[7]);
                a[8]  = fmaf(xv, w2[0], a[8]);   a[9]  = fmaf(xv, w2[1], a[9]);
                a[10] = fmaf(xv, w2[2], a[10]);  a[11] = fmaf(xv, w2[3], a[11]);
                a[12] = fmaf(xv, w3[0], a[12]);  a[13] = fmaf(xv, w3[1], a[13]);
                a[14] = fmaf(xv, w3[2], a[14]);  a[15] = fmaf(xv, w3[3], a[15]);
                a[16] = fmaf(xv, w4[0], a[16]);  a[17] = fmaf(xv, w4[1], a[17]);
            }
        }
    }
    __syncthreads();               // done reading weights; reuse smem
    #pragma unroll
    for (int i = 0; i < 18; i++) smem[t * 21 + i] = a[i];   // [cq*64+px][21]
    __syncthreads();

    for (int task = t; task < 576; task += 256) {
        int p2 = task & 63, n = task >> 6;
        float ay = b_off[n], ax = b_off[9 + n];
        #pragma unroll
        for (int c2 = 0; c2 < 4; c2++) {
            ay += smem[(c2 * 64 + p2) * 21 + n];
            ax += smem[(c2 * 64 + p2) * 21 + 9 + n];
        }
        float py  = (float)(y + (n / 3)) + ay;            // y+1 + (n/3-1)
        float pxc = (float)(x0 + p2 + (n % 3)) + ax;      // x+1 + (n%3-1)
        float fy = floorf(py), fx = floorf(pxc);
        if (py  < 1.f || py  > 128.f) py  = fy;
        if (pxc < 1.f || pxc > 128.f) pxc = fx;
        py  = fminf(fmaxf(py,  0.f), 129.f);
        pxc = fminf(fmaxf(pxc, 0.f), 129.f);
        float2 o; o.x = py; o.y = pxc;
        pT[n * TOTPX + (b * HH + y) * WW + x0 + p2] = o;
    }
}

// ------- K2: NHWC bilinear gather -> swizzled bf16 LDS -> MFMA GEMM -------
// Block: 256 thr, 64 px (half row) x 128 oc. Wave tile: 32oc x 64px.
__global__ __launch_bounds__(256, 4) void k_main(
    const float* __restrict__ xT, const unsigned short* __restrict__ wsW,
    const float2* __restrict__ pT, float* __restrict__ out)
{
    __shared__ __align__(16) short Al[4096];   // 8KB [64px][64ch] bf16, XOR-swizzled

    int bid0 = blockIdx.x;                     // XCD-bijective: 1024 = 8 x 128
    int bid  = ((bid0 & 7) << 7) | (bid0 >> 3);
    int b = bid >> 8, rem = bid & 255, y = rem >> 1, x0 = (rem & 1) << 6;

    int t = threadIdx.x, lane = t & 63, wv = t >> 6;
    int pxq = lane >> 4, chs = lane & 15;      // gather: 4px-quad x 16 ch-slices
    int row = lane & 15, koct = lane >> 4;     // mfma fragment role

    const float* xb = xT + (size_t)b * (HWSZ * 64) + (chs << 2);
    int pixbase = (b * HH + y) * WW + x0;

    f32x4 acc[2][4];
    #pragma unroll
    for (int i = 0; i < 2; i++)
        #pragma unroll
        for (int j = 0; j < 4; j++) acc[i][j] = {0.f, 0.f, 0.f, 0.f};

    for (int kc = 0; kc < 9; kc++) {
        // ---- gather: sample n=kc; each lane: 4 ch of one pixel, 4 corners ----
        #pragma unroll
        for (int q4 = 0; q4 < 4; q4++) {
            int pl = wv * 16 + q4 * 4 + pxq;
            float2 p = pT[kc * TOTPX + pixbase + pl];
            float fy = floorf(p.x), fx = floorf(p.y);
            int y0 = (int)fy, x0i = (int)fx;           // in [0,129]
            int y1 = min(y0 + 1, 129), x1 = min(x0i + 1, 129);
            float wyl = 1.f + (fy - p.x);
            float wyr = 1.f - ((float)y1 - p.x);
            float wxl = 1.f + (fx - p.y);
            float wxr = 1.f - ((float)x1 - p.y);
            float glt = wyl * wxl, grb = wyr * wxr, glb = wyl * wxr, grt = wyr * wxl;
            if ((unsigned)(y0  - 1) >= 128u) { glt = 0.f; glb = 0.f; }
            if ((unsigned)(y1  - 1) >= 128u) { grb = 0.f; grt = 0.f; }
            if ((unsigned)(x0i - 1) >= 128u) { glt = 0.f; grt = 0.f; }
            if ((unsigned)(x1  - 1) >= 128u) { grb = 0.f; glb = 0.f; }
            int ry0 = min(max(y0 - 1, 0), 127), ry1 = min(max(y1 - 1, 0), 127);
            int rx0 = min(max(x0i - 1, 0), 127), rx1 = min(max(x1 - 1, 0), 127);
            f32x4 v00 = *(const f32x4*)(xb + ((ry0 * WW + rx0) << 6));
            f32x4 v11 = *(const f32x4*)(xb + ((ry1 * WW + rx1) << 6));
            f32x4 v01 = *(const f32x4*)(xb + ((ry0 * WW + rx1) << 6));
            f32x4 v10 = *(const f32x4*)(xb + ((ry1 * WW + rx0) << 6));
            f32x4 v = v00 * glt + v11 * grb + v01 * glb + v10 * grt;
            unsigned u0 = f2bf(v[0]) | (f2bf(v[1]) << 16);
            unsigned u1 = f2bf(v[2]) | (f2bf(v[3]) << 16);
            int addr = pl * 128 + (((chs >> 1) ^ (pl & 7)) << 4) + ((chs & 1) << 3);
            uint2 u; u.x = u0; u.y = u1;
            *(uint2*)((char*)Al + addr) = u;
        }
        __syncthreads();

        // ---- MFMA: W frags direct from L1-resident bf16 chunk ----
        const unsigned short* wchunk = wsW + kc * (CO * 64);
        #pragma unroll
        for (int ks = 0; ks < 2; ks++) {
            short8 af[2], bf[4];
            #pragma unroll
            for (int i = 0; i < 2; i++)
                af[i] = *(const short8*)(wchunk + (wv * 32 + i * 16 + row) * 64
                                         + ks * 32 + koct * 8);
            #pragma unroll
            for (int j = 0; j < 4; j++) {
                int pl = j * 16 + row;
                bf[j] = *(const short8*)((const char*)Al + pl * 128
                                         + (((ks * 4 + koct) ^ (pl & 7)) << 4));
            }
            #pragma unroll
            for (int i = 0; i < 2; i++)
                #pragma unroll
                for (int j = 0; j < 4; j++)
                    acc[i][j] = __builtin_amdgcn_mfma_f32_16x16x32_bf16(
                        af[i], bf[j], acc[i][j], 0, 0, 0);
        }
        __syncthreads();
    }

    // ---- epilogue: D row->oc, col->px ----
    int obase = b * CO * HWSZ + y * WW + x0;
    #pragma unroll
    for (int i = 0; i < 2; i++)
        #pragma unroll
        for (int j = 0; j < 4; j++)
            #pragma unroll
            for (int r = 0; r < 4; r++) {
                int oc = wv * 32 + i * 16 + koct * 4 + r;
                out[obase + oc * HWSZ + j * 16 + row] = acc[i][j][r];
            }
}

extern "C" void kernel_launch(void* const* d_in, const int* in_sizes, int n_in,
                              void* d_out, int out_size, void* d_ws, size_t ws_size,
                              hipStream_t stream) {
    const float* x      = (const float*)d_in[0];
    const float* w_off  = (const float*)d_in[1];
    const float* b_off  = (const float*)d_in[2];
    const float* w_conv = (const float*)d_in[3];
    float* out = (float*)d_out;

    float*          xT  = (float*)d_ws;                                  // 16 MB
    float2*         pT  = (float2*)((char*)d_ws + (size_t)TOTPX * 64 * 4);       // 4.5 MB
    unsigned short* wsW = (unsigned short*)((char*)d_ws + (size_t)TOTPX * 64 * 4
                                            + (size_t)NN * TOTPX * 8);   // 144 KB

    k_prep_w<<<(CO * 576 + 255) / 256, 256, 0, stream>>>(w_conv, wsW);
    k_nhwc<<<1024, 256, 0, stream>>>(x, xT);
    k_offsets<<<1024, 256, 0, stream>>>(x, w_off, b_off, pT);
    k_main<<<1024, 256, 0, stream>>>(xT, wsW, pT, out);
}